// Round 3
// baseline (392.457 us; speedup 1.0000x reference)
//
#include <hip/hip_runtime.h>

#define B_ 8
#define L_ 4800
#define H_ 8
#define D_ 64
#define BH_ 64

// ---------------------------------------------------------------------------
// Kernel A (gram): one WAVE per (b,h,chunk).  No LDS, no barriers in the hot
// loop: each lane reads its q-fragment (q[r][r0..r0+7]) and k-fragment
// (k[r][c0..c0+7]) straight from global.  8-lane groups share 32-B segments
// (hardware dedups broadcast), each cache line is consumed exactly once by
// exactly one wave -> clean streaming.  8x8 register outer-product tile.
// ---------------------------------------------------------------------------
__global__ __launch_bounds__(256) void gram_kernel(
    const float* __restrict__ q, const float* __restrict__ k,
    float* __restrict__ Gp, float* __restrict__ qsqp, float* __restrict__ ksqp,
    const int P, const int CL)
{
  const int t = threadIdx.x;
  const int w = t >> 6, lane = t & 63;
  const int wid = blockIdx.x * 4 + w;          // 0 .. 64*P-1
  const int bh = wid / P;
  const int p  = wid - bh * P;
  const int b = bh >> 3, h = bh & 7;
  const int r0 = (lane >> 3) * 8;              // q-dim octet
  const int c0 = (lane & 7) * 8;               // k-dim octet

  const float* qb = q + ((size_t)b * L_ + (size_t)p * CL) * 512 + h * 64;
  const float* kb = k + ((size_t)b * L_ + (size_t)p * CL) * 512 + h * 64;

  float accG[8][8] = {};
  float sqq[8] = {0,0,0,0,0,0,0,0};
  float sqk[8] = {0,0,0,0,0,0,0,0};

#pragma unroll 2
  for (int r = 0; r < CL; ++r) {
    const float* qr = qb + (size_t)r * 512;
    const float* kr = kb + (size_t)r * 512;
    float4 qa0 = *(const float4*)(qr + r0);
    float4 qa1 = *(const float4*)(qr + r0 + 4);
    float4 kv0 = *(const float4*)(kr + c0);
    float4 kv1 = *(const float4*)(kr + c0 + 4);
    float av[8] = {qa0.x,qa0.y,qa0.z,qa0.w,qa1.x,qa1.y,qa1.z,qa1.w};
    float bv[8] = {kv0.x,kv0.y,kv0.z,kv0.w,kv1.x,kv1.y,kv1.z,kv1.w};
#pragma unroll
    for (int i = 0; i < 8; i++)
#pragma unroll
      for (int j = 0; j < 8; j++)
        accG[i][j] = fmaf(av[i], bv[j], accG[i][j]);
#pragma unroll
    for (int j = 0; j < 8; j++) sqq[j] = fmaf(av[j], av[j], sqq[j]);
#pragma unroll
    for (int j = 0; j < 8; j++) sqk[j] = fmaf(bv[j], bv[j], sqk[j]);
  }

  // Gram partial (wave-private output, scatter-merges in L2)
  float* gout = Gp + ((size_t)bh * P + p) * 4096;
#pragma unroll
  for (int i = 0; i < 8; i++) {
    *(float4*)(gout + (r0 + i) * 64 + c0) =
        make_float4(accG[i][0], accG[i][1], accG[i][2], accG[i][3]);
    *(float4*)(gout + (r0 + i) * 64 + c0 + 4) =
        make_float4(accG[i][4], accG[i][5], accG[i][6], accG[i][7]);
  }

  // sum-of-squares: sqq duplicated across c0-groups (take c0==0 reps),
  // sqk duplicated across r0-groups (take r0==0 reps, i.e. lanes 0..7).
  __shared__ float sqs[4][2][64];
  if ((lane & 7) == 0) {
#pragma unroll
    for (int j = 0; j < 8; j++) sqs[w][0][r0 + j] = sqq[j];
  }
  if (lane < 8) {
#pragma unroll
    for (int j = 0; j < 8; j++) sqs[w][1][c0 + j] = sqk[j];
  }
  __syncthreads();
  qsqp[((size_t)bh * P + p) * 64 + lane] = sqs[w][0][lane];
  ksqp[((size_t)bh * P + p) * 64 + lane] = sqs[w][1][lane];
}

// ---------------------------------------------------------------------------
// Kernel B (reduce): sum the P partial Grams + sq partials at full bandwidth.
// grid (8, 64): 512 blocks x 128 threads, each block owns 512 floats of one bh.
// ---------------------------------------------------------------------------
__global__ __launch_bounds__(128) void reduce_kernel(
    const float* __restrict__ Gp, const float* __restrict__ qsqp,
    const float* __restrict__ ksqp, float* __restrict__ Gt,
    float* __restrict__ qst, float* __restrict__ kst, const int P)
{
  const int j8 = blockIdx.x;
  const int bh = blockIdx.y;
  const int t = threadIdx.x;
  const size_t off = (size_t)j8 * 512 + (size_t)t * 4;
  const float* gp = Gp + (size_t)bh * P * 4096 + off;

  float4 a0 = make_float4(0.f,0.f,0.f,0.f);
  float4 a1 = make_float4(0.f,0.f,0.f,0.f);
  float4 a2 = make_float4(0.f,0.f,0.f,0.f);
  float4 a3 = make_float4(0.f,0.f,0.f,0.f);
  int p = 0;
  for (; p + 4 <= P; p += 4) {
    float4 g0 = *(const float4*)(gp + (size_t)(p + 0) * 4096);
    float4 g1 = *(const float4*)(gp + (size_t)(p + 1) * 4096);
    float4 g2 = *(const float4*)(gp + (size_t)(p + 2) * 4096);
    float4 g3 = *(const float4*)(gp + (size_t)(p + 3) * 4096);
    a0.x += g0.x; a0.y += g0.y; a0.z += g0.z; a0.w += g0.w;
    a1.x += g1.x; a1.y += g1.y; a1.z += g1.z; a1.w += g1.w;
    a2.x += g2.x; a2.y += g2.y; a2.z += g2.z; a2.w += g2.w;
    a3.x += g3.x; a3.y += g3.y; a3.z += g3.z; a3.w += g3.w;
  }
  for (; p < P; p++) {
    float4 g = *(const float4*)(gp + (size_t)p * 4096);
    a0.x += g.x; a0.y += g.y; a0.z += g.z; a0.w += g.w;
  }
  float4 r = make_float4(a0.x + a1.x + a2.x + a3.x,
                         a0.y + a1.y + a2.y + a3.y,
                         a0.z + a1.z + a2.z + a3.z,
                         a0.w + a1.w + a2.w + a3.w);
  *(float4*)(Gt + (size_t)bh * 4096 + off) = r;

  if (j8 == 0) {
    const int d2 = t & 63;
    const float* sp = (t < 64) ? qsqp : ksqp;
    const float* s = sp + (size_t)bh * P * 64 + d2;
    float x0 = 0.f, x1 = 0.f, x2 = 0.f, x3 = 0.f;
    int pp = 0;
    for (; pp + 4 <= P; pp += 4) {
      x0 += s[(size_t)(pp + 0) * 64];
      x1 += s[(size_t)(pp + 1) * 64];
      x2 += s[(size_t)(pp + 2) * 64];
      x3 += s[(size_t)(pp + 3) * 64];
    }
    for (; pp < P; pp++) x0 += s[(size_t)pp * 64];
    float* dst = (t < 64) ? qst : kst;
    dst[bh * 64 + d2] = x0 + x1 + x2 + x3;
  }
}

// ---------------------------------------------------------------------------
// Kernel C (mask): per (b,h) 64x64 postprocessing (normalize, gates,
// temperature, 4x exact top-k + masked softmax).  Verified logic; writes the
// combined mask TRANSPOSED (Mt[e][d]) with coalesced stores.
// ---------------------------------------------------------------------------
__global__ __launch_bounds__(256) void mask_kernel(
    const float* __restrict__ Gt, const float* __restrict__ qst,
    const float* __restrict__ kst,
    const float* __restrict__ temperature, const float* __restrict__ attns,
    const float* __restrict__ row_w, const float* __restrict__ row_b,
    const float* __restrict__ col_w, const float* __restrict__ col_b,
    float* __restrict__ Mt)
{
  const int bh = blockIdx.x;
  const int h = bh & 7;
  const int t = threadIdx.x;
  const int d = t & 63, q4 = t >> 6;
  const int e0 = q4 * 16;

  __shared__ float att[64][65];
  __shared__ float rnq[64], rnk[64], cw[64], rw[64];
  __shared__ float wcol[64], wrow[64];
  __shared__ float thr[4][64];
  __shared__ float pmax[4][64];
  __shared__ float rowmax[64];
  __shared__ float psum[4][4][64];
  __shared__ float rinv[4][64];

  if (t < 64) {
    rnq[t] = 1.0f / fmaxf(sqrtf(qst[bh * 64 + t]), 1e-12f);
  } else if (t < 128) {
    rnk[t - 64] = 1.0f / fmaxf(sqrtf(kst[bh * 64 + (t - 64)]), 1e-12f);
  } else if (t < 192) {
    cw[t - 128] = col_w[t - 128];
  } else {
    rw[t - 192] = row_w[t - 192];
  }
  __syncthreads();

  {
    const float rq = rnq[d];
#pragma unroll
    for (int ee = 0; ee < 16; ee += 4) {
      float4 g = *(const float4*)&Gt[(size_t)bh * 4096 + d * 64 + e0 + ee];
      att[d][e0+ee+0] = g.x * rq * rnk[e0+ee+0];
      att[d][e0+ee+1] = g.y * rq * rnk[e0+ee+1];
      att[d][e0+ee+2] = g.z * rq * rnk[e0+ee+2];
      att[d][e0+ee+3] = g.w * rq * rnk[e0+ee+3];
    }
  }
  __syncthreads();

  if (t < 64) {
    float s = 0.f;
    for (int c = 0; c < 64; c++) s += att[c][t] * cw[c];
    s += col_b[0];
    wcol[t] = 1.0f / (1.0f + __expf(-s));
  } else if (t < 128) {
    int c = t - 64;
    float s = 0.f;
    for (int e = 0; e < 64; e++) s += att[c][e] * rw[e];
    s += row_b[0];
    wrow[c] = 1.0f / (1.0f + __expf(-s));
  }
  __syncthreads();

  {
    const float temp = temperature[h];
    const float wr = wrow[d];
    float mx = -1e30f;
#pragma unroll
    for (int ee = 0; ee < 16; ee++) {
      float x = att[d][e0+ee] * ((wcol[e0+ee] + wr) * temp);
      att[d][e0+ee] = x;
      mx = fmaxf(mx, x);
    }
    pmax[q4][d] = mx;
  }
  __syncthreads();
  if (t < 64)
    rowmax[t] = fmaxf(fmaxf(pmax[0][t], pmax[1][t]), fmaxf(pmax[2][t], pmax[3][t]));

  // exact k-th largest by rank counting (tie-exact like lax.top_k)
  {
    float x[16];
#pragma unroll
    for (int j = 0; j < 16; j++) x[j] = att[d][e0+j];
    int gt[16] = {}, ge[16] = {};
    for (int m = 0; m < 64; m++) {
      float y = att[d][m];
#pragma unroll
      for (int j = 0; j < 16; j++) { gt[j] += (y > x[j]); ge[j] += (y >= x[j]); }
    }
    const int tks[4] = {32, 42, 48, 51};
#pragma unroll
    for (int j = 0; j < 16; j++)
#pragma unroll
      for (int i = 0; i < 4; i++)
        if (gt[j] <= tks[i]-1 && ge[j] >= tks[i]) thr[i][d] = x[j];
  }
  __syncthreads();

  {
    const float rm = rowmax[d];
    const float t0 = thr[0][d], t1 = thr[1][d], t2 = thr[2][d], t3 = thr[3][d];
    float s0=0.f, s1=0.f, s2=0.f, s3=0.f;
#pragma unroll
    for (int ee = 0; ee < 16; ee++) {
      float xv = att[d][e0+ee];
      float ex = __expf(xv - rm);
      if (xv >= t0) s0 += ex;
      if (xv >= t1) s1 += ex;
      if (xv >= t2) s2 += ex;
      if (xv >= t3) s3 += ex;
    }
    psum[q4][0][d] = s0; psum[q4][1][d] = s1; psum[q4][2][d] = s2; psum[q4][3][d] = s3;
  }
  __syncthreads();
  if (t < 64) {
#pragma unroll
    for (int i = 0; i < 4; i++) {
      float s = psum[0][i][t] + psum[1][i][t] + psum[2][i][t] + psum[3][i][t];
      rinv[i][t] = attns[i] / s;
    }
  }
  __syncthreads();

  {
    const float rm = rowmax[d];
    const float t0 = thr[0][d], t1 = thr[1][d], t2 = thr[2][d], t3 = thr[3][d];
    const float r0 = rinv[0][d], r1 = rinv[1][d], r2 = rinv[2][d], r3 = rinv[3][d];
    float* mo = Mt + (size_t)bh * 4096;
#pragma unroll
    for (int ee = 0; ee < 16; ee++) {
      float xv = att[d][e0+ee];
      float ex = __expf(xv - rm);
      float m = 0.f;
      if (xv >= t0) m += r0 * ex;
      if (xv >= t1) m += r1 * ex;
      if (xv >= t2) m += r2 * ex;
      if (xv >= t3) m += r3 * ex;
      mo[(e0 + ee) * 64 + d] = m;       // transposed: Mt[e][d]
    }
  }
}

// ---------------------------------------------------------------------------
// Kernel D (apply): out[b,l,h,:] = A * v[b,l,h,:] with A[d][e] = Mt[e][d].
// Lane = one token.  acc[64] statically indexed; e-loop runtime with per-lane
// float4 v loads.  M rows are WAVE-UNIFORM addresses -> scalar (s_load) path,
// SGPR-operand FMAs, zero LDS, zero barriers.
// ---------------------------------------------------------------------------
__global__ __launch_bounds__(256) void apply_kernel(
    const float* __restrict__ Mt, const float* __restrict__ v,
    float* __restrict__ out)
{
  const int bh = blockIdx.y;
  const int b = bh >> 3, h = bh & 7;
  const int l = blockIdx.x * 256 + threadIdx.x;
  const bool ok = (l < L_);
  const float* __restrict__ Mb = Mt + (size_t)bh * 4096;
  const float* vrow = v + (((size_t)b * L_ + (size_t)(ok ? l : 0)) * 8 + h) * 64;

  float acc[64];
#pragma unroll
  for (int d = 0; d < 64; d++) acc[d] = 0.f;

  for (int e4 = 0; e4 < 16; ++e4) {
    float4 vv = *(const float4*)(vrow + e4 * 4);
#pragma unroll
    for (int j = 0; j < 4; ++j) {
      const float4* mr = (const float4*)(Mb + (e4 * 4 + j) * 64);
      const float vj = (j == 0) ? vv.x : (j == 1) ? vv.y : (j == 2) ? vv.z : vv.w;
#pragma unroll
      for (int d4 = 0; d4 < 16; ++d4) {
        float4 m = mr[d4];
        acc[d4*4+0] = fmaf(m.x, vj, acc[d4*4+0]);
        acc[d4*4+1] = fmaf(m.y, vj, acc[d4*4+1]);
        acc[d4*4+2] = fmaf(m.z, vj, acc[d4*4+2]);
        acc[d4*4+3] = fmaf(m.w, vj, acc[d4*4+3]);
      }
    }
  }

  if (ok) {
    float* orow = out + (((size_t)b * L_ + l) * 8 + h) * 64;
#pragma unroll
    for (int d4 = 0; d4 < 16; ++d4)
      *(float4*)(orow + d4 * 4) =
          make_float4(acc[d4*4+0], acc[d4*4+1], acc[d4*4+2], acc[d4*4+3]);
  }
}

// ---------------------------------------------------------------------------
extern "C" void kernel_launch(void* const* d_in, const int* in_sizes, int n_in,
                              void* d_out, int out_size, void* d_ws, size_t ws_size,
                              hipStream_t stream) {
  const float* q           = (const float*)d_in[0];
  const float* k           = (const float*)d_in[1];
  const float* v           = (const float*)d_in[2];
  const float* temperature = (const float*)d_in[3];
  const float* attns       = (const float*)d_in[4];
  const float* row_w       = (const float*)d_in[5];
  const float* row_b       = (const float*)d_in[6];
  const float* col_w       = (const float*)d_in[7];
  const float* col_b       = (const float*)d_in[8];
  float* out = (float*)d_out;

  // P = chunks per (b,h); chunk length CL = L/P.  ws need in floats:
  // Gp 64*P*4096 + qsqp/ksqp 2*64*P*64 + Gt 262144 + qst/kst 8192 + Mt 262144
  auto needB = [](long long P) -> size_t {
    return (size_t)(270336LL * P + 532480LL) * 4u;
  };
  int P = 48;
  if (ws_size < needB(48)) P = 24;
  if (ws_size < needB(24)) P = 12;
  const int CL = L_ / P;

  float* ws = (float*)d_ws;
  const size_t GPs = (size_t)64 * P * 4096;
  const size_t SQs = (size_t)64 * P * 64;
  float* Gp   = ws;
  float* qsqp = Gp + GPs;
  float* ksqp = qsqp + SQs;
  float* Gt   = ksqp + SQs;        // 64*4096
  float* qst  = Gt + 262144;       // 64*64
  float* kst  = qst + 4096;        // 64*64
  float* Mt   = kst + 4096;        // 64*4096 (transposed mask)

  gram_kernel<<<dim3(16 * P, 1), 256, 0, stream>>>(q, k, Gp, qsqp, ksqp, P, CL);
  reduce_kernel<<<dim3(8, BH_), 128, 0, stream>>>(Gp, qsqp, ksqp, Gt, qst, kst, P);
  mask_kernel<<<dim3(BH_), 256, 0, stream>>>(Gt, qst, kst, temperature, attns,
                                             row_w, row_b, col_w, col_b, Mt);
  apply_kernel<<<dim3((L_ + 255) / 256, BH_), 256, 0, stream>>>(Mt, v, out);
}

// Round 4
// 326.901 us; speedup vs baseline: 1.2005x; 1.2005x over previous
//
#include <hip/hip_runtime.h>

#define B_ 8
#define L_ 4800
#define H_ 8
#define D_ 64
#define BH_ 64

// ---------------------------------------------------------------------------
// Kernel A (gram): round-0 proven structure (wave-private LDS slabs, no
// barriers in the K-loop, double-buffered register relay), with DOUBLED grid
// (P=30 chunks of 160 tokens) so LDS (5 blocks/CU at 32 KB) — not the grid —
// sets occupancy: 1920 blocks = 7.5/CU vs round-0's 3.75/CU @ 21% occ.
// ---------------------------------------------------------------------------
__global__ __launch_bounds__(256) void gram_kernel(
    const float* __restrict__ q, const float* __restrict__ k,
    float* __restrict__ Gp, float* __restrict__ qsqp, float* __restrict__ ksqp,
    const int P, const int NS)
{
  const int bh = blockIdx.y;
  const int b = bh >> 3, h = bh & 7;
  const int cx = blockIdx.x;
  const int l0 = cx * (NS * 32);       // chunk = NS slabs/wave * 4 waves * 8 rows
  const int t = threadIdx.x;
  const int w = t >> 6, lane = t & 63;

  __shared__ float Ls[4][2][2][8][64];   // [wave][buf][q/k][row][d] = 32 KB

  const int lrow = lane >> 4;          // 0..3 (row within half-slab)
  const int lcol = (lane & 15) * 4;    // 0..60
  const int r0 = (lane >> 3) * 8;      // acc tile rows
  const int c0 = (lane & 7) * 8;       // acc tile cols

  const float* qb = q + (size_t)(b*L_)*512 + h*64;
  const float* kb = k + (size_t)(b*L_)*512 + h*64;

  float accG[8][8] = {};
  float sqq[4] = {0,0,0,0}, sqk[4] = {0,0,0,0};

  // preload + stage slab 0 (wave's slabs: l0 + (w + 4*s)*8)
  {
    const int ls = l0 + w*8;
    const float* qp = qb + (size_t)(ls + lrow)*512 + lcol;
    const float* kp = kb + (size_t)(ls + lrow)*512 + lcol;
    float4 a0 = *(const float4*)qp;
    float4 a1 = *(const float4*)(qp + 4*512);
    float4 b0 = *(const float4*)kp;
    float4 b1 = *(const float4*)(kp + 4*512);
    sqq[0]+=a0.x*a0.x; sqq[1]+=a0.y*a0.y; sqq[2]+=a0.z*a0.z; sqq[3]+=a0.w*a0.w;
    sqq[0]+=a1.x*a1.x; sqq[1]+=a1.y*a1.y; sqq[2]+=a1.z*a1.z; sqq[3]+=a1.w*a1.w;
    sqk[0]+=b0.x*b0.x; sqk[1]+=b0.y*b0.y; sqk[2]+=b0.z*b0.z; sqk[3]+=b0.w*b0.w;
    sqk[0]+=b1.x*b1.x; sqk[1]+=b1.y*b1.y; sqk[2]+=b1.z*b1.z; sqk[3]+=b1.w*b1.w;
    *(float4*)&Ls[w][0][0][lrow  ][lcol] = a0;
    *(float4*)&Ls[w][0][0][lrow+4][lcol] = a1;
    *(float4*)&Ls[w][0][1][lrow  ][lcol] = b0;
    *(float4*)&Ls[w][0][1][lrow+4][lcol] = b1;
  }

  for (int s = 0; s < NS; s++) {
    const int cur = s & 1;
    float4 a0, a1, b0, b1;
    if (s + 1 < NS) {               // issue next-slab global loads early
      const int ls = l0 + (w + 4*(s+1))*8;
      const float* qp = qb + (size_t)(ls + lrow)*512 + lcol;
      const float* kp = kb + (size_t)(ls + lrow)*512 + lcol;
      a0 = *(const float4*)qp;
      a1 = *(const float4*)(qp + 4*512);
      b0 = *(const float4*)kp;
      b1 = *(const float4*)(kp + 4*512);
    }
    // compute current slab (wave-private; compiler inserts lgkmcnt only)
    const float (*Lq)[64] = Ls[w][cur][0];
    const float (*Lk)[64] = Ls[w][cur][1];
#pragma unroll
    for (int r = 0; r < 8; r++) {
      float4 qa0 = *(const float4*)&Lq[r][r0];
      float4 qa1 = *(const float4*)&Lq[r][r0+4];
      float4 kb0 = *(const float4*)&Lk[r][c0];
      float4 kb1 = *(const float4*)&Lk[r][c0+4];
      float av[8] = {qa0.x,qa0.y,qa0.z,qa0.w,qa1.x,qa1.y,qa1.z,qa1.w};
      float bv[8] = {kb0.x,kb0.y,kb0.z,kb0.w,kb1.x,kb1.y,kb1.z,kb1.w};
#pragma unroll
      for (int i = 0; i < 8; i++)
#pragma unroll
        for (int j = 0; j < 8; j++)
          accG[i][j] = fmaf(av[i], bv[j], accG[i][j]);
    }
    if (s + 1 < NS) {
      sqq[0]+=a0.x*a0.x; sqq[1]+=a0.y*a0.y; sqq[2]+=a0.z*a0.z; sqq[3]+=a0.w*a0.w;
      sqq[0]+=a1.x*a1.x; sqq[1]+=a1.y*a1.y; sqq[2]+=a1.z*a1.z; sqq[3]+=a1.w*a1.w;
      sqk[0]+=b0.x*b0.x; sqk[1]+=b0.y*b0.y; sqk[2]+=b0.z*b0.z; sqk[3]+=b0.w*b0.w;
      sqk[0]+=b1.x*b1.x; sqk[1]+=b1.y*b1.y; sqk[2]+=b1.z*b1.z; sqk[3]+=b1.w*b1.w;
      *(float4*)&Ls[w][cur^1][0][lrow  ][lcol] = a0;
      *(float4*)&Ls[w][cur^1][0][lrow+4][lcol] = a1;
      *(float4*)&Ls[w][cur^1][1][lrow  ][lcol] = b0;
      *(float4*)&Ls[w][cur^1][1][lrow+4][lcol] = b1;
    }
  }

  // ---- cross-wave reduction (staging LDS reused as 4 x 2048-float scratch) ----
  float* red = &Ls[0][0][0][0][0];
  float4* redf4 = (float4*)red;
  float* gout = Gp + ((size_t)bh*P + cx)*4096;

  __syncthreads();
  // pass A: global rows 0..31
  if (r0 < 32) {
#pragma unroll
    for (int i = 0; i < 8; i++) {
      *(float4*)&red[w*2048 + (r0+i)*64 + c0    ] = make_float4(accG[i][0],accG[i][1],accG[i][2],accG[i][3]);
      *(float4*)&red[w*2048 + (r0+i)*64 + c0 + 4] = make_float4(accG[i][4],accG[i][5],accG[i][6],accG[i][7]);
    }
  }
  __syncthreads();
#pragma unroll
  for (int pp = 0; pp < 2; pp++) {
    int fi = t + pp*256;
    float4 s0 = redf4[fi], s1 = redf4[512+fi], s2 = redf4[1024+fi], s3 = redf4[1536+fi];
    float4 r; r.x = s0.x+s1.x+s2.x+s3.x; r.y = s0.y+s1.y+s2.y+s3.y;
    r.z = s0.z+s1.z+s2.z+s3.z; r.w = s0.w+s1.w+s2.w+s3.w;
    *(float4*)&gout[fi*4] = r;
  }
  __syncthreads();
  // pass B: global rows 32..63
  if (r0 >= 32) {
#pragma unroll
    for (int i = 0; i < 8; i++) {
      *(float4*)&red[w*2048 + (r0-32+i)*64 + c0    ] = make_float4(accG[i][0],accG[i][1],accG[i][2],accG[i][3]);
      *(float4*)&red[w*2048 + (r0-32+i)*64 + c0 + 4] = make_float4(accG[i][4],accG[i][5],accG[i][6],accG[i][7]);
    }
  }
  __syncthreads();
#pragma unroll
  for (int pp = 0; pp < 2; pp++) {
    int fi = t + pp*256;
    float4 s0 = redf4[fi], s1 = redf4[512+fi], s2 = redf4[1024+fi], s3 = redf4[1536+fi];
    float4 r; r.x = s0.x+s1.x+s2.x+s3.x; r.y = s0.y+s1.y+s2.y+s3.y;
    r.z = s0.z+s1.z+s2.z+s3.z; r.w = s0.w+s1.w+s2.w+s3.w;
    *(float4*)&gout[2048 + fi*4] = r;
  }
  __syncthreads();
  // sum-of-squares partials
  redf4[w*64 + lane]       = make_float4(sqq[0],sqq[1],sqq[2],sqq[3]);
  redf4[256 + w*64 + lane] = make_float4(sqk[0],sqk[1],sqk[2],sqk[3]);
  __syncthreads();
  if (t < 128) {
    const int d = t & 63;
    const int col4 = d >> 2, c = d & 3;
    const int base = (t < 64) ? 0 : 1024;   // float offset into red
    float s = 0.f;
#pragma unroll
    for (int ww = 0; ww < 4; ww++)
#pragma unroll
      for (int m = 0; m < 4; m++)
        s += red[base + (ww*64 + m*16 + col4)*4 + c];
    float* dst = (t < 64) ? qsqp : ksqp;
    dst[((size_t)bh*P + cx)*64 + d] = s;
  }
}

// ---------------------------------------------------------------------------
// Kernel B (reduce): sum the P partial Grams + sq partials at full bandwidth.
// grid (8, 64): 512 blocks x 128 threads, each block owns 512 floats of one bh.
// ---------------------------------------------------------------------------
__global__ __launch_bounds__(128) void reduce_kernel(
    const float* __restrict__ Gp, const float* __restrict__ qsqp,
    const float* __restrict__ ksqp, float* __restrict__ Gt,
    float* __restrict__ qst, float* __restrict__ kst, const int P)
{
  const int j8 = blockIdx.x;
  const int bh = blockIdx.y;
  const int t = threadIdx.x;
  const size_t off = (size_t)j8 * 512 + (size_t)t * 4;
  const float* gp = Gp + (size_t)bh * P * 4096 + off;

  float4 a0 = make_float4(0.f,0.f,0.f,0.f);
  float4 a1 = make_float4(0.f,0.f,0.f,0.f);
  float4 a2 = make_float4(0.f,0.f,0.f,0.f);
  float4 a3 = make_float4(0.f,0.f,0.f,0.f);
  int p = 0;
  for (; p + 4 <= P; p += 4) {
    float4 g0 = *(const float4*)(gp + (size_t)(p + 0) * 4096);
    float4 g1 = *(const float4*)(gp + (size_t)(p + 1) * 4096);
    float4 g2 = *(const float4*)(gp + (size_t)(p + 2) * 4096);
    float4 g3 = *(const float4*)(gp + (size_t)(p + 3) * 4096);
    a0.x += g0.x; a0.y += g0.y; a0.z += g0.z; a0.w += g0.w;
    a1.x += g1.x; a1.y += g1.y; a1.z += g1.z; a1.w += g1.w;
    a2.x += g2.x; a2.y += g2.y; a2.z += g2.z; a2.w += g2.w;
    a3.x += g3.x; a3.y += g3.y; a3.z += g3.z; a3.w += g3.w;
  }
  for (; p < P; p++) {
    float4 g = *(const float4*)(gp + (size_t)p * 4096);
    a0.x += g.x; a0.y += g.y; a0.z += g.z; a0.w += g.w;
  }
  float4 r = make_float4(a0.x + a1.x + a2.x + a3.x,
                         a0.y + a1.y + a2.y + a3.y,
                         a0.z + a1.z + a2.z + a3.z,
                         a0.w + a1.w + a2.w + a3.w);
  *(float4*)(Gt + (size_t)bh * 4096 + off) = r;

  if (j8 == 0) {
    const int d2 = t & 63;
    const float* sp = (t < 64) ? qsqp : ksqp;
    const float* s = sp + (size_t)bh * P * 64 + d2;
    float x0 = 0.f, x1 = 0.f, x2 = 0.f, x3 = 0.f;
    int pp = 0;
    for (; pp + 4 <= P; pp += 4) {
      x0 += s[(size_t)(pp + 0) * 64];
      x1 += s[(size_t)(pp + 1) * 64];
      x2 += s[(size_t)(pp + 2) * 64];
      x3 += s[(size_t)(pp + 3) * 64];
    }
    for (; pp < P; pp++) x0 += s[(size_t)pp * 64];
    float* dst = (t < 64) ? qst : kst;
    dst[bh * 64 + d2] = x0 + x1 + x2 + x3;
  }
}

// ---------------------------------------------------------------------------
// Kernel C (mask): per (b,h) 64x64 postprocessing (normalize, gates,
// temperature, 4x exact top-k + masked softmax).  Verified logic; writes the
// combined mask TRANSPOSED (Mt[e][d]) with coalesced stores.
// ---------------------------------------------------------------------------
__global__ __launch_bounds__(256) void mask_kernel(
    const float* __restrict__ Gt, const float* __restrict__ qst,
    const float* __restrict__ kst,
    const float* __restrict__ temperature, const float* __restrict__ attns,
    const float* __restrict__ row_w, const float* __restrict__ row_b,
    const float* __restrict__ col_w, const float* __restrict__ col_b,
    float* __restrict__ Mt)
{
  const int bh = blockIdx.x;
  const int h = bh & 7;
  const int t = threadIdx.x;
  const int d = t & 63, q4 = t >> 6;
  const int e0 = q4 * 16;

  __shared__ float att[64][65];
  __shared__ float rnq[64], rnk[64], cw[64], rw[64];
  __shared__ float wcol[64], wrow[64];
  __shared__ float thr[4][64];
  __shared__ float pmax[4][64];
  __shared__ float rowmax[64];
  __shared__ float psum[4][4][64];
  __shared__ float rinv[4][64];

  if (t < 64) {
    rnq[t] = 1.0f / fmaxf(sqrtf(qst[bh * 64 + t]), 1e-12f);
  } else if (t < 128) {
    rnk[t - 64] = 1.0f / fmaxf(sqrtf(kst[bh * 64 + (t - 64)]), 1e-12f);
  } else if (t < 192) {
    cw[t - 128] = col_w[t - 128];
  } else {
    rw[t - 192] = row_w[t - 192];
  }
  __syncthreads();

  {
    const float rq = rnq[d];
#pragma unroll
    for (int ee = 0; ee < 16; ee += 4) {
      float4 g = *(const float4*)&Gt[(size_t)bh * 4096 + d * 64 + e0 + ee];
      att[d][e0+ee+0] = g.x * rq * rnk[e0+ee+0];
      att[d][e0+ee+1] = g.y * rq * rnk[e0+ee+1];
      att[d][e0+ee+2] = g.z * rq * rnk[e0+ee+2];
      att[d][e0+ee+3] = g.w * rq * rnk[e0+ee+3];
    }
  }
  __syncthreads();

  if (t < 64) {
    float s = 0.f;
    for (int c = 0; c < 64; c++) s += att[c][t] * cw[c];
    s += col_b[0];
    wcol[t] = 1.0f / (1.0f + __expf(-s));
  } else if (t < 128) {
    int c = t - 64;
    float s = 0.f;
    for (int e = 0; e < 64; e++) s += att[c][e] * rw[e];
    s += row_b[0];
    wrow[c] = 1.0f / (1.0f + __expf(-s));
  }
  __syncthreads();

  {
    const float temp = temperature[h];
    const float wr = wrow[d];
    float mx = -1e30f;
#pragma unroll
    for (int ee = 0; ee < 16; ee++) {
      float x = att[d][e0+ee] * ((wcol[e0+ee] + wr) * temp);
      att[d][e0+ee] = x;
      mx = fmaxf(mx, x);
    }
    pmax[q4][d] = mx;
  }
  __syncthreads();
  if (t < 64)
    rowmax[t] = fmaxf(fmaxf(pmax[0][t], pmax[1][t]), fmaxf(pmax[2][t], pmax[3][t]));

  // exact k-th largest by rank counting (tie-exact like lax.top_k)
  {
    float x[16];
#pragma unroll
    for (int j = 0; j < 16; j++) x[j] = att[d][e0+j];
    int gt[16] = {}, ge[16] = {};
    for (int m = 0; m < 64; m++) {
      float y = att[d][m];
#pragma unroll
      for (int j = 0; j < 16; j++) { gt[j] += (y > x[j]); ge[j] += (y >= x[j]); }
    }
    const int tks[4] = {32, 42, 48, 51};
#pragma unroll
    for (int j = 0; j < 16; j++)
#pragma unroll
      for (int i = 0; i < 4; i++)
        if (gt[j] <= tks[i]-1 && ge[j] >= tks[i]) thr[i][d] = x[j];
  }
  __syncthreads();

  {
    const float rm = rowmax[d];
    const float t0 = thr[0][d], t1 = thr[1][d], t2 = thr[2][d], t3 = thr[3][d];
    float s0=0.f, s1=0.f, s2=0.f, s3=0.f;
#pragma unroll
    for (int ee = 0; ee < 16; ee++) {
      float xv = att[d][e0+ee];
      float ex = __expf(xv - rm);
      if (xv >= t0) s0 += ex;
      if (xv >= t1) s1 += ex;
      if (xv >= t2) s2 += ex;
      if (xv >= t3) s3 += ex;
    }
    psum[q4][0][d] = s0; psum[q4][1][d] = s1; psum[q4][2][d] = s2; psum[q4][3][d] = s3;
  }
  __syncthreads();
  if (t < 64) {
#pragma unroll
    for (int i = 0; i < 4; i++) {
      float s = psum[0][i][t] + psum[1][i][t] + psum[2][i][t] + psum[3][i][t];
      rinv[i][t] = attns[i] / s;
    }
  }
  __syncthreads();

  {
    const float rm = rowmax[d];
    const float t0 = thr[0][d], t1 = thr[1][d], t2 = thr[2][d], t3 = thr[3][d];
    const float r0 = rinv[0][d], r1 = rinv[1][d], r2 = rinv[2][d], r3 = rinv[3][d];
    float* mo = Mt + (size_t)bh * 4096;
#pragma unroll
    for (int ee = 0; ee < 16; ee++) {
      float xv = att[d][e0+ee];
      float ex = __expf(xv - rm);
      float m = 0.f;
      if (xv >= t0) m += r0 * ex;
      if (xv >= t1) m += r1 * ex;
      if (xv >= t2) m += r2 * ex;
      if (xv >= t3) m += r3 * ex;
      mo[(e0 + ee) * 64 + d] = m;       // transposed: Mt[e][d]
    }
  }
}

// ---------------------------------------------------------------------------
// Kernel D (apply): out[b,l,h,:] = A * v[b,l,h,:] with A[d][e] = Mt[e][d].
// One wave per 64-token tile; v tile in LDS with XOR bank swizzle
// (conflict-free ds_read_b128); Mt rows read from global (1 MB, L2-hot).
// Verified in round 2.
// ---------------------------------------------------------------------------
__global__ __launch_bounds__(64, 2) void apply_kernel(
    const float* __restrict__ Mt, const float* __restrict__ v,
    float* __restrict__ out)
{
  const int bh = blockIdx.y;
  const int b = bh >> 3, h = bh & 7;
  const int l0 = blockIdx.x * 64;
  const int lane = threadIdx.x;

  __shared__ float Vs[64][68];          // [token][e] with col ^= ((token>>3)<<2)

  // stage v tile: 64 tokens x 64 dims (4 x 256B contiguous segments / instr)
  const int tg  = lane >> 4;
  const int e0w = (lane & 15) * 4;
#pragma unroll
  for (int it = 0; it < 16; it++) {
    const int tl = it * 4 + tg;
    float4 x = *(const float4*)(v + (((size_t)b * L_ + l0 + tl) * 8 + h) * 64 + e0w);
    const int cs = e0w ^ ((tl >> 3) << 2);   // 4-aligned XOR keeps float4 intact
    *(float4*)&Vs[tl][cs] = x;
  }
  __syncthreads();

  const int dg = lane >> 3, lg = lane & 7;
  const int d0 = dg * 8;
  float acc[8][8] = {};                 // [token jj][dim i]
  const float* Mtb = Mt + (size_t)bh * 4096;

  for (int e = 0; e < 64; e += 4) {
    float mt[4][8];
#pragma unroll
    for (int j = 0; j < 4; j++) {
      float4 m0 = *(const float4*)(Mtb + (e + j) * 64 + d0);
      float4 m1 = *(const float4*)(Mtb + (e + j) * 64 + d0 + 4);
      mt[j][0]=m0.x; mt[j][1]=m0.y; mt[j][2]=m0.z; mt[j][3]=m0.w;
      mt[j][4]=m1.x; mt[j][5]=m1.y; mt[j][6]=m1.z; mt[j][7]=m1.w;
    }
#pragma unroll
    for (int jj = 0; jj < 8; jj++) {
      const int tl = lg * 8 + jj;
      const int cs = e ^ (lg << 2);     // tl>>3 == lg
      float4 vv = *(const float4*)&Vs[tl][cs];
#pragma unroll
      for (int i = 0; i < 8; i++) {
        acc[jj][i] = fmaf(mt[0][i], vv.x, acc[jj][i]);
        acc[jj][i] = fmaf(mt[1][i], vv.y, acc[jj][i]);
        acc[jj][i] = fmaf(mt[2][i], vv.z, acc[jj][i]);
        acc[jj][i] = fmaf(mt[3][i], vv.w, acc[jj][i]);
      }
    }
  }

#pragma unroll
  for (int jj = 0; jj < 8; jj++) {
    const int tl = lg * 8 + jj;
    float* orow = out + (((size_t)b * L_ + l0 + tl) * 8 + h) * 64 + d0;
    *(float4*)(orow)     = make_float4(acc[jj][0], acc[jj][1], acc[jj][2], acc[jj][3]);
    *(float4*)(orow + 4) = make_float4(acc[jj][4], acc[jj][5], acc[jj][6], acc[jj][7]);
  }
}

// ---------------------------------------------------------------------------
extern "C" void kernel_launch(void* const* d_in, const int* in_sizes, int n_in,
                              void* d_out, int out_size, void* d_ws, size_t ws_size,
                              hipStream_t stream) {
  const float* q           = (const float*)d_in[0];
  const float* k           = (const float*)d_in[1];
  const float* v           = (const float*)d_in[2];
  const float* temperature = (const float*)d_in[3];
  const float* attns       = (const float*)d_in[4];
  const float* row_w       = (const float*)d_in[5];
  const float* row_b       = (const float*)d_in[6];
  const float* col_w       = (const float*)d_in[7];
  const float* col_b       = (const float*)d_in[8];
  float* out = (float*)d_out;

  // P = chunks per (b,h).  ws need (floats) = 270336*P + 532480
  auto needB = [](long long P) -> size_t {
    return (size_t)(270336LL * P + 532480LL) * 4u;
  };
  int P = 30;
  if (ws_size < needB(30)) P = 15;
  const int NS = L_ / (P * 32);        // per-wave slabs per chunk (5 or 10)

  float* ws = (float*)d_ws;
  const size_t GPs = (size_t)64 * P * 4096;
  const size_t SQs = (size_t)64 * P * 64;
  float* Gp   = ws;
  float* qsqp = Gp + GPs;
  float* ksqp = qsqp + SQs;
  float* Gt   = ksqp + SQs;        // 64*4096
  float* qst  = Gt + 262144;       // 64*64
  float* kst  = qst + 4096;        // 64*64
  float* Mt   = kst + 4096;        // 64*4096 (transposed mask)

  gram_kernel<<<dim3(P, BH_), 256, 0, stream>>>(q, k, Gp, qsqp, ksqp, P, NS);
  reduce_kernel<<<dim3(8, BH_), 128, 0, stream>>>(Gp, qsqp, ksqp, Gt, qst, kst, P);
  mask_kernel<<<dim3(BH_), 256, 0, stream>>>(Gt, qst, kst, temperature, attns,
                                             row_w, row_b, col_w, col_b, Mt);
  apply_kernel<<<dim3(L_ / 64, BH_), 64, 0, stream>>>(Mt, v, out);
}